// Round 8
// baseline (292.848 us; speedup 1.0000x reference)
//
#include <hip/hip_runtime.h>
#include <hip/hip_bf16.h>
#include <cstddef>

// Problem constants
constexpr int BS = 2;
constexpr int N  = 256;
constexpr int D  = 256;   // NH_N
constexpr int E  = 128;   // NH_E
constexpr int YD = 128;   // NH_Y
constexpr float RSQRT_F = 0.17677669529663687f;  // 1/sqrt(32)

typedef __attribute__((ext_vector_type(8))) short     short8;
typedef __attribute__((ext_vector_type(4))) float     f32x4;
typedef __attribute__((ext_vector_type(4))) unsigned short u16x4;
typedef __attribute__((ext_vector_type(8))) unsigned short u16x8;

__device__ __forceinline__ unsigned short f2bf(float x) {
    unsigned u = __float_as_uint(x);
    unsigned r = (u + 0x7fffu + ((u >> 16) & 1u)) >> 16;   // RNE
    return (unsigned short)r;
}
__device__ __forceinline__ float bf2f(unsigned short h) {
    return __uint_as_float(((unsigned)h) << 16);
}
__device__ __forceinline__ f32x4 mfma16(short8 a, short8 b, f32x4 c) {
    return __builtin_amdgcn_mfma_f32_16x16x32_bf16(a, b, c, 0, 0, 0);
}

// ---------------------------------------------------------------------------
// PREP (fused): qkv + wt + ymap + zx  (za_part now lives inside main_kernel)
// grid 600 x 256:
//   [0,192)    qkv   (Q fp32; K/V -> kvJ bf16 interleaved)
//   [192,576)  wt    (weight transpose + bf16)
//   [576,584)  ymap
//   [584,600)  zx
// ---------------------------------------------------------------------------
__global__ __launch_bounds__(256) void prep_kernel(
        const float* __restrict__ x,
        const float* __restrict__ y,
        const float* __restrict__ qw, const float* __restrict__ qb,
        const float* __restrict__ kw, const float* __restrict__ kb,
        const float* __restrict__ vw, const float* __restrict__ vb,
        const float* __restrict__ Wadd, const float* __restrict__ Wmul,
        const float* __restrict__ W2,
        const float* __restrict__ we_add, const float* __restrict__ be_add,
        const float* __restrict__ we_mul, const float* __restrict__ be_mul,
        const float* __restrict__ wx_add, const float* __restrict__ bx_add,
        const float* __restrict__ wx_mul, const float* __restrict__ bx_mul,
        float* __restrict__ Q, unsigned short* __restrict__ kvJ,
        unsigned short* __restrict__ WaddT, unsigned short* __restrict__ WmulT,
        unsigned short* __restrict__ W2T,
        float* __restrict__ ye1, float* __restrict__ ye2,
        float* __restrict__ yx1, float* __restrict__ yx2,
        float* __restrict__ zx) {
    const int blk = blockIdx.x;
    const int tid = threadIdx.x;
    __shared__ float smem[2048];

    if (blk < 192) {
        // ---- qkv ----
        const int m  = blk >> 6;
        const int rg = blk & 63;
        const float* W = (m == 0) ? qw : (m == 1) ? kw : vw;
        const float* B = (m == 0) ? qb : (m == 1) ? kb : vb;
        float (*xs)[D] = (float(*)[D])smem;
#pragma unroll
        for (int r = 0; r < 8; ++r)
            xs[r][tid] = x[(size_t)(rg * 8 + r) * D + tid];
        __syncthreads();
        float acc[8];
        const float bb = B[tid];
#pragma unroll
        for (int r = 0; r < 8; ++r) acc[r] = bb;
        for (int k = 0; k < D; ++k) {
            const float w = W[k * D + tid];
#pragma unroll
            for (int r = 0; r < 8; ++r) acc[r] += xs[r][k] * w;
        }
#pragma unroll
        for (int r = 0; r < 8; ++r) {
            const int row = rg * 8 + r;
            if (m == 0) Q[(size_t)row * D + tid] = acc[r];
            else        kvJ[((size_t)row * D + tid) * 2 + (m - 1)] = f2bf(acc[r]);
        }
    } else if (blk < 576) {
        // ---- wt ----
        int idx = (blk - 192) * 256 + tid;
        int s = idx >> 15;
        int k = idx & 32767;
        if (s == 0)      { int f = k >> 7, e = k & 127; WaddT[k] = f2bf(Wadd[e * 256 + f]); }
        else if (s == 1) { int f = k >> 7, e = k & 127; WmulT[k] = f2bf(Wmul[e * 256 + f]); }
        else             { int f = k & 255, e = k >> 8; W2T[k]   = f2bf(W2[f * 128 + e]); }
    } else if (blk < 584) {
        // ---- ymap ----
        const int bb = (blk - 576) >> 2;
        const int m  = (blk - 576) & 3;
        const float* W; const float* B; float* O;
        switch (m) {
            case 0:  W = we_add; B = be_add; O = ye1; break;
            case 1:  W = we_mul; B = be_mul; O = ye2; break;
            case 2:  W = wx_add; B = bx_add; O = yx1; break;
            default: W = wx_mul; B = bx_mul; O = yx2; break;
        }
        float acc = B[tid];
        for (int k = 0; k < YD; ++k)
            acc += y[bb * YD + k] * W[k * D + tid];
        O[bb * D + tid] = acc;
    } else {
        // ---- zx : block = (b, f-chunk of 32); 8-way i-split ----
        const int bb = (blk - 584) >> 3;
        const int fc = (blk - 584) & 7;
        const int fl = tid & 31;
        const int ig = tid >> 5;
        const int f  = fc * 32 + fl;
        float s = 0.f, ss = 0.f, mn = INFINITY, mx = -INFINITY;
        for (int i = ig * 32; i < ig * 32 + 32; ++i) {
            const float v = x[((size_t)bb * N + i) * D + f];
            s += v; ss += v * v; mn = fminf(mn, v); mx = fmaxf(mx, v);
        }
        smem[0 * 256 + ig * 32 + fl] = s;
        smem[1 * 256 + ig * 32 + fl] = ss;
        smem[2 * 256 + ig * 32 + fl] = mn;
        smem[3 * 256 + ig * 32 + fl] = mx;
        __syncthreads();
        if (ig == 0) {
#pragma unroll
            for (int gg = 1; gg < 8; ++gg) {
                s += smem[0 * 256 + gg * 32 + fl]; ss += smem[1 * 256 + gg * 32 + fl];
                mn = fminf(mn, smem[2 * 256 + gg * 32 + fl]);
                mx = fmaxf(mx, smem[3 * 256 + gg * 32 + fl]);
            }
            const float M = 256.f;
            const float mean = s / M;
            const float var  = (ss - s * s / M) / (M - 1.f);
            zx[bb * 1024 + f]       = mean;
            zx[bb * 1024 + 256 + f] = mn;
            zx[bb * 1024 + 512 + f] = mx;
            zx[bb * 1024 + 768 + f] = sqrtf(fmaxf(var, 0.f));
        }
    }
}

// ---------------------------------------------------------------------------
// MAIN: block = one (b,i). 8 waves, (512,1). 4 passes x 64 j; one barrier
// per pass. GEMM1 weights (waf/wmf, 64 VGPR) hoisted across passes; W2
// reloaded per pass from L2 (frees 32 regs). a staged to LDS bf16 (read
// from HBM exactly once), with fused za running stats (sum/sumsq/min/max).
// ---------------------------------------------------------------------------
__global__ __launch_bounds__(512, 1) void main_kernel(
        const float* __restrict__ a,
        const unsigned short* __restrict__ WaddT, const float* __restrict__ Badd,
        const unsigned short* __restrict__ WmulT, const float* __restrict__ Bmul,
        const unsigned short* __restrict__ W2T,  const float* __restrict__ AoutB,
        const float* __restrict__ Q, const unsigned short* __restrict__ kvJ,
        const float* __restrict__ ye1, const float* __restrict__ ye2,
        float* __restrict__ ahat, float* __restrict__ wV,
        float* __restrict__ psum, float* __restrict__ psumsq,
        float* __restrict__ pmin, float* __restrict__ pmax) {
    const int bi = blockIdx.x;         // b*256 + i
    const int b  = bi >> 8;
    const int tid  = threadIdx.x;
    const int lane = tid & 63;
    const int w    = tid >> 6;         // wave id 0..7
    const int l15  = lane & 15;
    const int lk   = lane >> 4;        // 0..3

    __shared__ unsigned short abuf[2][64 * 128];   // 2 x 16 KB  a-tile bf16 (swizzled)
    __shared__ unsigned short hbuf[2][64 * 256];   // 2 x 32 KB  h bf16 (swizzled)

    const float* arow = a + (size_t)bi * (N * E);
    float* ahatp      = ahat + (size_t)bi * (N * E);
    const unsigned short* kvb = kvJ + (size_t)b * N * D * 2;

    // ---- hoist GEMM1 weight fragments (pass-invariant) ----
    short8 waf[4][2], wmf[4][2];
#pragma unroll
    for (int ks = 0; ks < 4; ++ks)
#pragma unroll
        for (int m_ = 0; m_ < 2; ++m_) {
            const int frow = w * 32 + m_ * 16 + l15;
            waf[ks][m_] = *(const short8*)(WaddT + frow * 128 + ks * 32 + lk * 8);
            wmf[ks][m_] = *(const short8*)(WmulT + frow * 128 + ks * 32 + lk * 8);
        }

    // per-f constants: f = w*32 + m_*16 + lk*4 + r  (fi = m_*4+r)
    float qs[8], e1c[8], e2c[8], b1c[8], b2c[8];
#pragma unroll
    for (int m_ = 0; m_ < 2; ++m_) {
        const int f0 = w * 32 + m_ * 16 + lk * 4;
        const f32x4 qv  = *(const f32x4*)(Q + (size_t)bi * D + f0);
        const f32x4 a1  = *(const f32x4*)(ye1 + b * D + f0);
        const f32x4 a2  = *(const f32x4*)(ye2 + b * D + f0);
        const f32x4 bb1 = *(const f32x4*)(Badd + f0);
        const f32x4 bb2 = *(const f32x4*)(Bmul + f0);
#pragma unroll
        for (int r = 0; r < 4; ++r) {
            const int fi = m_ * 4 + r;
            qs[fi]  = qv[r] * RSQRT_F;
            e1c[fi] = a1[r];
            e2c[fi] = a2[r] + 1.f;
            b1c[fi] = bb1[r] + 1.f;   // (a1 + 1) bias
            b2c[fi] = bb2[r];
        }
    }
    const f32x4 bias2 = *(const f32x4*)(AoutB + w * 16 + lk * 4);   // GEMM2 e-tile = w

    // softmax accumulators (no max tracking: |Y| <~ 2.5 by construction)
    float sm_l[8], sm_a[8];
#pragma unroll
    for (int q = 0; q < 8; ++q) { sm_l[q] = 0.f; sm_a[q] = 0.f; }

    // za running stats: this thread's 4 e's (e = echunk*4 + r)
    f32x4 st_s  = (f32x4){0.f, 0.f, 0.f, 0.f};
    f32x4 st_ss = (f32x4){0.f, 0.f, 0.f, 0.f};
    f32x4 st_mn = (f32x4){INFINITY, INFINITY, INFINITY, INFINITY};
    f32x4 st_mx = (f32x4){-INFINITY, -INFINITY, -INFINITY, -INFINITY};

    // staging map: 512 thr x 4 rows x f32x4 = 64 rows x 128 floats
    const int echunk = tid & 31;       // e = echunk*4 .. +4
    const int rowgrp = tid >> 5;       // 0..15, rows rowgrp*4 .. +4

#define STAT4(v) { st_s += (v); \
                   st_ss.x = fmaf((v).x,(v).x,st_ss.x); st_ss.y = fmaf((v).y,(v).y,st_ss.y); \
                   st_ss.z = fmaf((v).z,(v).z,st_ss.z); st_ss.w = fmaf((v).w,(v).w,st_ss.w); \
                   st_mn.x = fminf(st_mn.x,(v).x); st_mn.y = fminf(st_mn.y,(v).y); \
                   st_mn.z = fminf(st_mn.z,(v).z); st_mn.w = fminf(st_mn.w,(v).w); \
                   st_mx.x = fmaxf(st_mx.x,(v).x); st_mx.y = fmaxf(st_mx.y,(v).y); \
                   st_mx.z = fmaxf(st_mx.z,(v).z); st_mx.w = fmaxf(st_mx.w,(v).w); }

    // prologue: stage rows 0..63 into abuf[0]
    {
        const float* ap = arow + (size_t)(rowgrp * 4) * E + echunk * 4;
#pragma unroll
        for (int rr = 0; rr < 4; ++rr) {
            const f32x4 v = *(const f32x4*)(ap + (size_t)rr * E);
            STAT4(v);
            u16x4 pk;
            pk.x = f2bf(v.x); pk.y = f2bf(v.y); pk.z = f2bf(v.z); pk.w = f2bf(v.w);
            const int row = rowgrp * 4 + rr;
            const unsigned addr = ((unsigned)(row * 256 + echunk * 8)) ^ ((unsigned)(row & 7) << 4);
            *(u16x4*)((char*)abuf[0] + addr) = pk;
        }
    }
    __syncthreads();

    for (int t = 0; t < 4; ++t) {
        const int j0 = t * 64;
        const unsigned short* ab = abuf[t & 1];
        unsigned short* hw = hbuf[t & 1];

        // prefetch next a-tile rows into registers (issue early)
        f32x4 p0, p1, p2, p3;
        if (t < 3) {
            const float* ap = arow + (size_t)(j0 + 64 + rowgrp * 4) * E + echunk * 4;
            p0 = *(const f32x4*)(ap);
            p1 = *(const f32x4*)(ap + E);
            p2 = *(const f32x4*)(ap + 2 * E);
            p3 = *(const f32x4*)(ap + 3 * E);
        }

        // ---- two 32-j halves: GEMM1 + phase B ----
#pragma unroll
        for (int h2 = 0; h2 < 2; ++h2) {
            // kv loads for this half (L2-hot)
            u16x8 kvv[2][2];
#pragma unroll
            for (int n_ = 0; n_ < 2; ++n_) {
                const int jg = j0 + h2 * 32 + n_ * 16 + l15;
#pragma unroll
                for (int m_ = 0; m_ < 2; ++m_)
                    kvv[n_][m_] = *(const u16x8*)(kvb + ((size_t)jg * D + w * 32 + m_ * 16 + lk * 4) * 2);
            }
            // GEMM1
            f32x4 acc1[2][2], acc2[2][2];
#pragma unroll
            for (int m_ = 0; m_ < 2; ++m_) {
                const f32x4 i1 = (f32x4){b1c[m_ * 4 + 0], b1c[m_ * 4 + 1], b1c[m_ * 4 + 2], b1c[m_ * 4 + 3]};
                const f32x4 i2 = (f32x4){b2c[m_ * 4 + 0], b2c[m_ * 4 + 1], b2c[m_ * 4 + 2], b2c[m_ * 4 + 3]};
#pragma unroll
                for (int n_ = 0; n_ < 2; ++n_) { acc1[m_][n_] = i1; acc2[m_][n_] = i2; }
            }
#pragma unroll
            for (int ks = 0; ks < 4; ++ks) {
                short8 bfrg[2];
#pragma unroll
                for (int n_ = 0; n_ < 2; ++n_) {
                    const int jloc = h2 * 32 + n_ * 16 + l15;
                    const unsigned baddr = ((unsigned)(jloc * 256 + (ks * 32 + lk * 8) * 2))
                                           ^ ((unsigned)(jloc & 7) << 4);
                    bfrg[n_] = *(const short8*)((const char*)ab + baddr);
                }
#pragma unroll
                for (int m_ = 0; m_ < 2; ++m_)
#pragma unroll
                    for (int n_ = 0; n_ < 2; ++n_) {
                        acc1[m_][n_] = mfma16(waf[ks][m_], bfrg[n_], acc1[m_][n_]);
                        acc2[m_][n_] = mfma16(wmf[ks][m_], bfrg[n_], acc2[m_][n_]);
                    }
            }
            // phase B
#pragma unroll
            for (int n_ = 0; n_ < 2; ++n_) {
                const int jloc = h2 * 32 + n_ * 16 + l15;
#pragma unroll
                for (int m_ = 0; m_ < 2; ++m_) {
                    u16x4 hp;
#pragma unroll
                    for (int r = 0; r < 4; ++r) {
                        const int fi = m_ * 4 + r;
                        const float kf = bf2f(kvv[n_][m_][2 * r]);
                        const float vf = bf2f(kvv[n_][m_][2 * r + 1]);
                        const float yv = qs[fi] * kf * acc1[m_][n_][r] + acc2[m_][n_][r];
                        hp[r] = f2bf(e1c[fi] + e2c[fi] * yv);
                        const float ev = __expf(yv);
                        sm_l[fi] += ev;
                        sm_a[fi] += ev * vf;
                    }
                    const unsigned haddr = ((unsigned)(jloc * 512 + (w * 32 + m_ * 16 + lk * 4) * 2))
                                           ^ ((unsigned)(jloc & 7) << 4);
                    *(u16x4*)((char*)hw + haddr) = hp;
                }
            }
        }

        // ---- stats + write prefetched a-tile to the other buffer ----
        if (t < 3) {
            STAT4(p0); STAT4(p1); STAT4(p2); STAT4(p3);
            unsigned short* nb = abuf[(t + 1) & 1];
            const f32x4 pv[4] = {p0, p1, p2, p3};
#pragma unroll
            for (int rr = 0; rr < 4; ++rr) {
                u16x4 pk;
                pk.x = f2bf(pv[rr].x); pk.y = f2bf(pv[rr].y);
                pk.z = f2bf(pv[rr].z); pk.w = f2bf(pv[rr].w);
                const int row = rowgrp * 4 + rr;
                const unsigned addr = ((unsigned)(row * 256 + echunk * 8)) ^ ((unsigned)(row & 7) << 4);
                *(u16x4*)((char*)nb + addr) = pk;
            }
        }
        __syncthreads();   // h ready; next a-tile ready; ab reads done

        // ---- GEMM2: ahat^T[e][j] = W2T . h^T (+bias), 64 j per wave ----
        short8 w2v[8];
#pragma unroll
        for (int ks = 0; ks < 8; ++ks)
            w2v[ks] = *(const short8*)(W2T + (w * 16 + l15) * 256 + ks * 32 + lk * 8);
        f32x4 accO[4];
#pragma unroll
        for (int n2 = 0; n2 < 4; ++n2) accO[n2] = bias2;
#pragma unroll
        for (int ks = 0; ks < 8; ++ks) {
            const int foff = ks * 32 + lk * 8;
#pragma unroll
            for (int n2 = 0; n2 < 4; ++n2) {
                const int jloc = n2 * 16 + l15;
                const unsigned haddr = ((unsigned)(jloc * 512 + foff * 2))
                                       ^ ((unsigned)(jloc & 7) << 4);
                const short8 hf = *(const short8*)((const char*)hw + haddr);
                accO[n2] = mfma16(w2v[ks], hf, accO[n2]);
            }
        }
        {
            const int eb = w * 16 + lk * 4;
#pragma unroll
            for (int n2 = 0; n2 < 4; ++n2) {
                const int jg2 = j0 + n2 * 16 + l15;
                *(f32x4*)(ahatp + (size_t)jg2 * E + eb) = accO[n2];
            }
        }
    }

    // ---- merge softmax partials across l15 (sum over j-columns) ----
#pragma unroll
    for (int st = 1; st <= 8; st <<= 1) {
#pragma unroll
        for (int fi = 0; fi < 8; ++fi) {
            sm_l[fi] += __shfl_xor(sm_l[fi], st, 64);
            sm_a[fi] += __shfl_xor(sm_a[fi], st, 64);
        }
    }
    if (l15 == 0) {
#pragma unroll
        for (int m_ = 0; m_ < 2; ++m_)
#pragma unroll
            for (int r = 0; r < 4; ++r) {
                const int fi = m_ * 4 + r;
                const int f  = w * 32 + m_ * 16 + lk * 4 + r;
                wV[(size_t)bi * D + f] = sm_a[fi] / sm_l[fi];
            }
    }

    // ---- za stats block reduction -> psum/psumsq/pmin/pmax[bi*128+e] ----
    // hbuf[0] region was last read at t=2's GEMM2 (before the t=3 barrier);
    // safe to reuse as fp32 scratch: 4 stats x 16 rowgrps x 128 e = 32 KB.
    {
        float* sc = (float*)hbuf;     // [stat][rowgrp][e] : stat*2048 + g*128 + e
        const int ebase = echunk * 4;
        *(f32x4*)(sc + 0 * 2048 + rowgrp * 128 + ebase) = st_s;
        *(f32x4*)(sc + 1 * 2048 + rowgrp * 128 + ebase) = st_ss;
        *(f32x4*)(sc + 2 * 2048 + rowgrp * 128 + ebase) = st_mn;
        *(f32x4*)(sc + 3 * 2048 + rowgrp * 128 + ebase) = st_mx;
        __syncthreads();
        if (tid < 128) {
            float s = 0.f, ss = 0.f, mn = INFINITY, mx = -INFINITY;
#pragma unroll
            for (int g = 0; g < 16; ++g) {
                s  += sc[0 * 2048 + g * 128 + tid];
                ss += sc[1 * 2048 + g * 128 + tid];
                mn = fminf(mn, sc[2 * 2048 + g * 128 + tid]);
                mx = fmaxf(mx, sc[3 * 2048 + g * 128 + tid]);
            }
            const int o = bi * E + tid;
            psum[o] = s; psumsq[o] = ss; pmin[o] = mn; pmax[o] = mx;
        }
    }
#undef STAT4
}

// ---------------------------------------------------------------------------
// POST (fused): xhat (blocks 0..63) + za_reduce (blocks 64..65). 256 thr.
// ---------------------------------------------------------------------------
__global__ __launch_bounds__(256) void post_kernel(
        const float* __restrict__ wV,
        const float* __restrict__ yx1, const float* __restrict__ yx2,
        const float* __restrict__ W, const float* __restrict__ B,
        const float* __restrict__ psum, const float* __restrict__ psumsq,
        const float* __restrict__ pmin, const float* __restrict__ pmax,
        float* __restrict__ xhat, float* __restrict__ za) {
    const int blk = blockIdx.x;
    const int tid = threadIdx.x;
    __shared__ float smem[2048];

    if (blk < 64) {
        // ---- xhat ----
        float (*xr)[D] = (float(*)[D])smem;
#pragma unroll
        for (int r = 0; r < 8; ++r) {
            const int row = blk * 8 + r;
            const int b = row >> 8;
            xr[r][tid] = yx1[b * D + tid] + (yx2[b * D + tid] + 1.f) * wV[(size_t)row * D + tid];
        }
        __syncthreads();
        float acc[8];
        const float bb = B[tid];
#pragma unroll
        for (int r = 0; r < 8; ++r) acc[r] = bb;
        for (int k = 0; k < D; ++k) {
            const float w = W[k * D + tid];
#pragma unroll
            for (int r = 0; r < 8; ++r) acc[r] += xr[r][k] * w;
        }
#pragma unroll
        for (int r = 0; r < 8; ++r)
            xhat[(size_t)(blk * 8 + r) * D + tid] = acc[r];
    } else {
        // ---- za_reduce : b = blk-64; 2-way i-split ----
        const int b = blk - 64;
        const int feat = tid & 127;
        const int g = tid >> 7;       // 0..1
        float s = 0.f, ss = 0.f, mn = INFINITY, mx = -INFINITY;
        for (int c = g * 128; c < g * 128 + 128; ++c) {
            const int o = (b * 256 + c) * E + feat;
            s += psum[o]; ss += psumsq[o];
            mn = fminf(mn, pmin[o]); mx = fmaxf(mx, pmax[o]);
        }
        smem[0 * 256 + g * 128 + feat] = s;
        smem[1 * 256 + g * 128 + feat] = ss;
        smem[2 * 256 + g * 128 + feat] = mn;
        smem[3 * 256 + g * 128 + feat] = mx;
        __syncthreads();
        if (g == 0) {
            s += smem[0 * 256 + 128 + feat]; ss += smem[1 * 256 + 128 + feat];
            mn = fminf(mn, smem[2 * 256 + 128 + feat]);
            mx = fmaxf(mx, smem[3 * 256 + 128 + feat]);
            const float M = 65536.f;
            const float mean = s / M;
            const float var  = (ss - s * s / M) / (M - 1.f);
            za[b * 512 + feat]       = mean;
            za[b * 512 + 128 + feat] = mn;
            za[b * 512 + 256 + feat] = mx;
            za[b * 512 + 384 + feat] = sqrtf(fmaxf(var, 0.f));
        }
    }
}

// ---------------------------------------------------------------------------
// yhat MLP — 512 threads, 4-way k-split + LDS reduce
// ---------------------------------------------------------------------------
__global__ void yhat_kernel(const float* __restrict__ y,
                            const float* __restrict__ za, const float* __restrict__ zx,
                            const float* __restrict__ yyw, const float* __restrict__ yyb,
                            const float* __restrict__ xyw, const float* __restrict__ xyb,
                            const float* __restrict__ ayw, const float* __restrict__ ayb,
                            const float* __restrict__ w1, const float* __restrict__ b1,
                            const float* __restrict__ w2, const float* __restrict__ b2,
                            float* __restrict__ out) {
    const int b = blockIdx.x;
    const int tid = threadIdx.x;
    const int o = tid & 127;
    const int q = tid >> 7;
    __shared__ float zy[1664];           // [y(128) | za(512) | zx(1024)]
    for (int idx = tid; idx < 1664; idx += 512) {
        float v;
        if (idx < 128)      v = y[b * YD + idx];
        else if (idx < 640) v = za[b * 512 + idx - 128];
        else                v = zx[b * 1024 + idx - 640];
        zy[idx] = v;
    }
    __syncthreads();
    float p = 0.f;
    if (q == 0) {
        for (int k = 0; k < 128; ++k) p += zy[k] * yyw[k * YD + o];
        for (int k = 0; k < 128; ++k) p += zy[128 + k] * ayw[k * YD + o];
    } else if (q == 1) {
        for (int k = 128; k < 512; ++k) p += zy[128 + k] * ayw[k * YD + o];
    } else if (q == 2) {
        for (int k = 0; k < 512; ++k) p += zy[640 + k] * xyw[k * YD + o];
    } else {
        for (int k = 512; k < 1024; ++k) p += zy[640 + k] * xyw[k * YD + o];
    }
    __shared__ float red[4][128];
    __shared__ float h1s[128], h2s[128];
    red[q][o] = p;
    __syncthreads();
    if (tid < 128) {
        h1s[o] = yyb[o] + xyb[o] + ayb[o] + red[0][o] + red[1][o] + red[2][o] + red[3][o];
    }
    __syncthreads();
    float p2 = 0.f;
    for (int k = q * 32; k < q * 32 + 32; ++k) p2 += h1s[k] * w1[k * YD + o];
    red[q][o] = p2;
    __syncthreads();
    if (tid < 128) h2s[o] = fmaxf(b1[o] + red[0][o] + red[1][o] + red[2][o] + red[3][o], 0.f);
    __syncthreads();
    float p3 = 0.f;
    for (int k = q * 32; k < q * 32 + 32; ++k) p3 += h2s[k] * w2[k * YD + o];
    red[q][o] = p3;
    __syncthreads();
    if (tid < 128) out[b * YD + o] = b2[o] + red[0][o] + red[1][o] + red[2][o] + red[3][o];
}

// ---------------------------------------------------------------------------
extern "C" void kernel_launch(void* const* d_in, const int* in_sizes, int n_in,
                              void* d_out, int out_size, void* d_ws, size_t ws_size,
                              hipStream_t stream) {
    const float* x         = (const float*)d_in[0];
    const float* a         = (const float*)d_in[1];
    const float* y         = (const float*)d_in[2];
    const float* qw        = (const float*)d_in[3];  const float* qb        = (const float*)d_in[4];
    const float* kw        = (const float*)d_in[5];  const float* kb        = (const float*)d_in[6];
    const float* vw        = (const float*)d_in[7];  const float* vb        = (const float*)d_in[8];
    const float* a2x_add_w = (const float*)d_in[9];  const float* a2x_add_b = (const float*)d_in[10];
    const float* a2x_mul_w = (const float*)d_in[11]; const float* a2x_mul_b = (const float*)d_in[12];
    const float* y2e_mul_w = (const float*)d_in[13]; const float* y2e_mul_b = (const float*)d_in[14];
    const float* y2e_add_w = (const float*)d_in[15]; const float* y2e_add_b = (const float*)d_in[16];
    const float* y2x_mul_w = (const float*)d_in[17]; const float* y2x_mul_b = (const float*)d_in[18];
    const float* y2x_add_w = (const float*)d_in[19]; const float* y2x_add_b = (const float*)d_in[20];
    const float* y_y_w     = (const float*)d_in[21]; const float* y_y_b     = (const float*)d_in[22];
    const float* x_y_w     = (const float*)d_in[23]; const float* x_y_b     = (const float*)d_in[24];
    const float* a_y_w     = (const float*)d_in[25]; const float* a_y_b     = (const float*)d_in[26];
    const float* x_out_w   = (const float*)d_in[27]; const float* x_out_b   = (const float*)d_in[28];
    const float* a_out_w   = (const float*)d_in[29]; const float* a_out_b   = (const float*)d_in[30];
    const float* y_out1_w  = (const float*)d_in[31]; const float* y_out1_b  = (const float*)d_in[32];
    const float* y_out2_w  = (const float*)d_in[33]; const float* y_out2_b  = (const float*)d_in[34];

    float* ws = (float*)d_ws;
    float* Q      = ws;                                   // 131072
    unsigned short* kvJ = (unsigned short*)(ws + 131072); // 262144 u16 = 131072 f
    float* wV     = ws + 262144;                          // 131072
    float* ye1    = ws + 393216;   // 512
    float* ye2    = ws + 393728;
    float* yx1    = ws + 394240;
    float* yx2    = ws + 394752;
    float* psum   = ws + 395264;   // 65536
    float* psumsq = ws + 460800;
    float* pminb  = ws + 526336;
    float* pmaxb  = ws + 591872;
    float* za     = ws + 657408;   // 1024
    float* zx     = ws + 658432;   // 2048
    unsigned short* WaddT = (unsigned short*)(ws + 660480);  // 32768 u16
    unsigned short* WmulT = (unsigned short*)(ws + 676864);
    unsigned short* W2T   = (unsigned short*)(ws + 693248);

    float* xhat = (float*)d_out;
    float* ahat = (float*)d_out + 131072;
    float* yhat = (float*)d_out + 16908288;

    prep_kernel<<<600, 256, 0, stream>>>(
        x, y, qw, qb, kw, kb, vw, vb,
        a2x_add_w, a2x_mul_w, a_out_w,
        y2e_add_w, y2e_add_b, y2e_mul_w, y2e_mul_b,
        y2x_add_w, y2x_add_b, y2x_mul_w, y2x_mul_b,
        Q, kvJ, WaddT, WmulT, W2T,
        ye1, ye2, yx1, yx2, zx);
    main_kernel<<<512, 512, 0, stream>>>(a, WaddT, a2x_add_b, WmulT, a2x_mul_b,
                                         W2T, a_out_b, Q, kvJ, ye1, ye2, ahat, wV,
                                         psum, psumsq, pminb, pmaxb);
    post_kernel<<<66, 256, 0, stream>>>(wV, yx1, yx2, x_out_w, x_out_b,
                                        psum, psumsq, pminb, pmaxb, xhat, za);
    yhat_kernel<<<2, 512, 0, stream>>>(y, za, zx, y_y_w, y_y_b, x_y_w, x_y_b, a_y_w, a_y_b,
                                       y_out1_w, y_out1_b, y_out2_w, y_out2_b, yhat);
}

// Round 9
// 152.704 us; speedup vs baseline: 1.9178x; 1.9178x over previous
//
#include <hip/hip_runtime.h>
#include <hip/hip_bf16.h>
#include <cstddef>

// Problem constants
constexpr int BS = 2;
constexpr int N  = 256;
constexpr int D  = 256;   // NH_N
constexpr int E  = 128;   // NH_E
constexpr int YD = 128;   // NH_Y
constexpr float RSQRT_F = 0.17677669529663687f;  // 1/sqrt(32)

typedef __attribute__((ext_vector_type(8))) short     short8;
typedef __attribute__((ext_vector_type(4))) float     f32x4;
typedef __attribute__((ext_vector_type(4))) unsigned short u16x4;
typedef __attribute__((ext_vector_type(8))) unsigned short u16x8;

__device__ __forceinline__ unsigned short f2bf(float x) {
    unsigned u = __float_as_uint(x);
    unsigned r = (u + 0x7fffu + ((u >> 16) & 1u)) >> 16;   // RNE
    return (unsigned short)r;
}
__device__ __forceinline__ float bf2f(unsigned short h) {
    return __uint_as_float(((unsigned)h) << 16);
}
__device__ __forceinline__ f32x4 mfma16(short8 a, short8 b, f32x4 c) {
    return __builtin_amdgcn_mfma_f32_16x16x32_bf16(a, b, c, 0, 0, 0);
}

// ---------------------------------------------------------------------------
// PREP (fused): qkv + wt + ymap + zx + za_part(vectorized)
// grid 1112 x 256:
//   [0,192)    qkv   (Q fp32; K/V -> kvJ bf16 interleaved)
//   [192,576)  wt    (weight transpose + bf16)
//   [576,584)  ymap
//   [584,600)  zx
//   [600,1112) za_part — f32x4 loads (16 B/lane), 8-way j-split + LDS reduce
// ---------------------------------------------------------------------------
__global__ __launch_bounds__(256) void prep_kernel(
        const float* __restrict__ x, const float* __restrict__ a,
        const float* __restrict__ y,
        const float* __restrict__ qw, const float* __restrict__ qb,
        const float* __restrict__ kw, const float* __restrict__ kb,
        const float* __restrict__ vw, const float* __restrict__ vb,
        const float* __restrict__ Wadd, const float* __restrict__ Wmul,
        const float* __restrict__ W2,
        const float* __restrict__ we_add, const float* __restrict__ be_add,
        const float* __restrict__ we_mul, const float* __restrict__ be_mul,
        const float* __restrict__ wx_add, const float* __restrict__ bx_add,
        const float* __restrict__ wx_mul, const float* __restrict__ bx_mul,
        float* __restrict__ Q, unsigned short* __restrict__ kvJ,
        unsigned short* __restrict__ WaddT, unsigned short* __restrict__ WmulT,
        unsigned short* __restrict__ W2T,
        float* __restrict__ ye1, float* __restrict__ ye2,
        float* __restrict__ yx1, float* __restrict__ yx2,
        float* __restrict__ psum, float* __restrict__ psumsq,
        float* __restrict__ pmin, float* __restrict__ pmax,
        float* __restrict__ zx) {
    const int blk = blockIdx.x;
    const int tid = threadIdx.x;
    __shared__ float smem[4096];

    if (blk < 192) {
        // ---- qkv ----
        const int m  = blk >> 6;
        const int rg = blk & 63;
        const float* W = (m == 0) ? qw : (m == 1) ? kw : vw;
        const float* B = (m == 0) ? qb : (m == 1) ? kb : vb;
        float (*xs)[D] = (float(*)[D])smem;
#pragma unroll
        for (int r = 0; r < 8; ++r)
            xs[r][tid] = x[(size_t)(rg * 8 + r) * D + tid];
        __syncthreads();
        float acc[8];
        const float bb = B[tid];
#pragma unroll
        for (int r = 0; r < 8; ++r) acc[r] = bb;
#pragma unroll 4
        for (int k = 0; k < D; ++k) {
            const float w = W[k * D + tid];
#pragma unroll
            for (int r = 0; r < 8; ++r) acc[r] += xs[r][k] * w;
        }
#pragma unroll
        for (int r = 0; r < 8; ++r) {
            const int row = rg * 8 + r;
            if (m == 0) Q[(size_t)row * D + tid] = acc[r];
            else        kvJ[((size_t)row * D + tid) * 2 + (m - 1)] = f2bf(acc[r]);
        }
    } else if (blk < 576) {
        // ---- wt ----
        int idx = (blk - 192) * 256 + tid;
        int s = idx >> 15;
        int k = idx & 32767;
        if (s == 0)      { int f = k >> 7, e = k & 127; WaddT[k] = f2bf(Wadd[e * 256 + f]); }
        else if (s == 1) { int f = k >> 7, e = k & 127; WmulT[k] = f2bf(Wmul[e * 256 + f]); }
        else             { int f = k & 255, e = k >> 8; W2T[k]   = f2bf(W2[f * 128 + e]); }
    } else if (blk < 584) {
        // ---- ymap ----
        const int bb = (blk - 576) >> 2;
        const int m  = (blk - 576) & 3;
        const float* W; const float* B; float* O;
        switch (m) {
            case 0:  W = we_add; B = be_add; O = ye1; break;
            case 1:  W = we_mul; B = be_mul; O = ye2; break;
            case 2:  W = wx_add; B = bx_add; O = yx1; break;
            default: W = wx_mul; B = bx_mul; O = yx2; break;
        }
        float acc = B[tid];
#pragma unroll 4
        for (int k = 0; k < YD; ++k)
            acc += y[bb * YD + k] * W[k * D + tid];
        O[bb * D + tid] = acc;
    } else if (blk < 600) {
        // ---- zx : block = (b, f-chunk of 32); 8-way i-split ----
        const int bb = (blk - 584) >> 3;
        const int fc = (blk - 584) & 7;
        const int fl = tid & 31;
        const int ig = tid >> 5;
        const int f  = fc * 32 + fl;
        float s = 0.f, ss = 0.f, mn = INFINITY, mx = -INFINITY;
#pragma unroll 4
        for (int i = ig * 32; i < ig * 32 + 32; ++i) {
            const float v = x[((size_t)bb * N + i) * D + f];
            s += v; ss += v * v; mn = fminf(mn, v); mx = fmaxf(mx, v);
        }
        smem[0 * 256 + ig * 32 + fl] = s;
        smem[1 * 256 + ig * 32 + fl] = ss;
        smem[2 * 256 + ig * 32 + fl] = mn;
        smem[3 * 256 + ig * 32 + fl] = mx;
        __syncthreads();
        if (ig == 0) {
#pragma unroll
            for (int gg = 1; gg < 8; ++gg) {
                s += smem[0 * 256 + gg * 32 + fl]; ss += smem[1 * 256 + gg * 32 + fl];
                mn = fminf(mn, smem[2 * 256 + gg * 32 + fl]);
                mx = fmaxf(mx, smem[3 * 256 + gg * 32 + fl]);
            }
            const float M = 256.f;
            const float mean = s / M;
            const float var  = (ss - s * s / M) / (M - 1.f);
            zx[bb * 1024 + f]       = mean;
            zx[bb * 1024 + 256 + f] = mn;
            zx[bb * 1024 + 512 + f] = mx;
            zx[bb * 1024 + 768 + f] = sqrtf(fmaxf(var, 0.f));
        }
    } else {
        // ---- za_part (vectorized): block = (b,i); thread (te,tj):
        //      e-quad te*4..+4, j in [tj*32, tj*32+32), f32x4 loads ----
        const int bi2 = blk - 600;            // b*256 + i
        const int te  = tid & 31;             // e-quad index
        const int tj  = tid >> 5;             // 0..7
        const float* base = a + (size_t)bi2 * N * E + te * 4;
        f32x4 s4  = (f32x4){0.f, 0.f, 0.f, 0.f};
        f32x4 ss4 = (f32x4){0.f, 0.f, 0.f, 0.f};
        f32x4 mn4 = (f32x4){INFINITY, INFINITY, INFINITY, INFINITY};
        f32x4 mx4 = (f32x4){-INFINITY, -INFINITY, -INFINITY, -INFINITY};
#pragma unroll 4
        for (int j = tj * 32; j < tj * 32 + 32; ++j) {
            const f32x4 v = *(const f32x4*)(base + (size_t)j * E);
            s4 += v;
            ss4.x = fmaf(v.x, v.x, ss4.x); ss4.y = fmaf(v.y, v.y, ss4.y);
            ss4.z = fmaf(v.z, v.z, ss4.z); ss4.w = fmaf(v.w, v.w, ss4.w);
            mn4.x = fminf(mn4.x, v.x); mn4.y = fminf(mn4.y, v.y);
            mn4.z = fminf(mn4.z, v.z); mn4.w = fminf(mn4.w, v.w);
            mx4.x = fmaxf(mx4.x, v.x); mx4.y = fmaxf(mx4.y, v.y);
            mx4.z = fmaxf(mx4.z, v.z); mx4.w = fmaxf(mx4.w, v.w);
        }
        // LDS reduce over tj: [stat][tj][128]
        *(f32x4*)(smem + (0 * 8 + tj) * 128 + te * 4) = s4;
        *(f32x4*)(smem + (1 * 8 + tj) * 128 + te * 4) = ss4;
        *(f32x4*)(smem + (2 * 8 + tj) * 128 + te * 4) = mn4;
        *(f32x4*)(smem + (3 * 8 + tj) * 128 + te * 4) = mx4;
        __syncthreads();
        if (tid < 128) {
            float s = 0.f, ss = 0.f, mn = INFINITY, mx = -INFINITY;
#pragma unroll
            for (int g = 0; g < 8; ++g) {
                s  += smem[(0 * 8 + g) * 128 + tid];
                ss += smem[(1 * 8 + g) * 128 + tid];
                mn = fminf(mn, smem[(2 * 8 + g) * 128 + tid]);
                mx = fmaxf(mx, smem[(3 * 8 + g) * 128 + tid]);
            }
            const int o = bi2 * E + tid;
            psum[o] = s; psumsq[o] = ss; pmin[o] = mn; pmax[o] = mx;
        }
    }
}

// ---------------------------------------------------------------------------
// MAIN (r6-proven): block = one (b,i). 8 waves, (512,1). 8 passes x 32 j.
// ALL weight fragments hoisted (waf/wmf/w2f = 96 VGPR). XCD-swizzled bi.
// ---------------------------------------------------------------------------
__global__ __launch_bounds__(512, 1) void main_kernel(
        const float* __restrict__ a,
        const unsigned short* __restrict__ WaddT, const float* __restrict__ Badd,
        const unsigned short* __restrict__ WmulT, const float* __restrict__ Bmul,
        const unsigned short* __restrict__ W2T,  const float* __restrict__ AoutB,
        const float* __restrict__ Q, const unsigned short* __restrict__ kvJ,
        const float* __restrict__ ye1, const float* __restrict__ ye2,
        float* __restrict__ ahat, float* __restrict__ wV) {
    // XCD-aware bijective swizzle (512 % 8 == 0): each XCD gets 64 consecutive bi
    const int bi = ((blockIdx.x & 7) << 6) | (blockIdx.x >> 3);
    const int b  = bi >> 8;
    const int tid  = threadIdx.x;
    const int lane = tid & 63;
    const int w    = tid >> 6;         // wave id 0..7
    const int l15  = lane & 15;
    const int lk   = lane >> 4;        // 0..3

    __shared__ unsigned short abuf[2][32 * 128];   // 2 x 8 KB  a-tile bf16 (swizzled)
    __shared__ unsigned short hbuf[2][32 * 256];   // 2 x 16 KB h bf16 (swizzled)

    const float* arow = a + (size_t)bi * (N * E);
    float* ahatp      = ahat + (size_t)bi * (N * E);
    const unsigned short* kvb = kvJ + (size_t)b * N * D * 2;

    // ---- hoist ALL weight fragments (pass-invariant) into registers ----
    short8 waf[4][2], wmf[4][2], w2f[8];
#pragma unroll
    for (int ks = 0; ks < 4; ++ks)
#pragma unroll
        for (int m_ = 0; m_ < 2; ++m_) {
            const int frow = w * 32 + m_ * 16 + l15;
            waf[ks][m_] = *(const short8*)(WaddT + frow * 128 + ks * 32 + lk * 8);
            wmf[ks][m_] = *(const short8*)(WmulT + frow * 128 + ks * 32 + lk * 8);
        }
#pragma unroll
    for (int ks = 0; ks < 8; ++ks)
        w2f[ks] = *(const short8*)(W2T + (w * 16 + l15) * 256 + ks * 32 + lk * 8);

    // hoisted per-f constants: f = w*32 + m_*16 + lk*4 + r  (fi = m_*4+r)
    float qs[8], e1c[8], e2c[8], b1c[8], b2c[8];
#pragma unroll
    for (int m_ = 0; m_ < 2; ++m_) {
        const int f0 = w * 32 + m_ * 16 + lk * 4;
        const f32x4 qv = *(const f32x4*)(Q + (size_t)bi * D + f0);
        const f32x4 a1 = *(const f32x4*)(ye1 + b * D + f0);
        const f32x4 a2 = *(const f32x4*)(ye2 + b * D + f0);
        const f32x4 bb1 = *(const f32x4*)(Badd + f0);
        const f32x4 bb2 = *(const f32x4*)(Bmul + f0);
#pragma unroll
        for (int r = 0; r < 4; ++r) {
            const int fi = m_ * 4 + r;
            qs[fi]  = qv[r] * RSQRT_F;
            e1c[fi] = a1[r];
            e2c[fi] = a2[r] + 1.f;
            b1c[fi] = bb1[r] + 1.f;   // (a1 + 1) bias
            b2c[fi] = bb2[r];
        }
    }
    const f32x4 bias2 = *(const f32x4*)(AoutB + w * 16 + lk * 4);

    // softmax accumulators (no max tracking: |Y| <~ 2.5 by construction)
    float sm_l[8], sm_a[8];
#pragma unroll
    for (int q = 0; q < 8; ++q) { sm_l[q] = 0.f; sm_a[q] = 0.f; }

    const int sjl = tid >> 4;          // staging row 0..31
    const int seq = tid & 15;          // staging 8-float chunk
    const unsigned saddr = ((unsigned)(sjl * 256 + seq * 16)) ^ ((unsigned)(sjl & 7) << 4);

    // prologue: stage pass 0
    {
        const float* ap = arow + (size_t)sjl * E + seq * 8;
        const f32x4 v0 = *(const f32x4*)ap;
        const f32x4 v1 = *(const f32x4*)(ap + 4);
        u16x8 pk;
        pk.s0 = f2bf(v0.x); pk.s1 = f2bf(v0.y); pk.s2 = f2bf(v0.z); pk.s3 = f2bf(v0.w);
        pk.s4 = f2bf(v1.x); pk.s5 = f2bf(v1.y); pk.s6 = f2bf(v1.z); pk.s7 = f2bf(v1.w);
        *(u16x8*)((char*)abuf[0] + saddr) = pk;
    }
    __syncthreads();

    for (int t = 0; t < 8; ++t) {
        const int j0 = t * 32;
        const unsigned short* ab = abuf[t & 1];
        unsigned short* hw = hbuf[t & 1];

        // issue global prefetches early: next a-tile (HBM) + this pass's kv (L2)
        f32x4 p0, p1;
        if (t < 7) {
            const float* ap = arow + (size_t)(j0 + 32 + sjl) * E + seq * 8;
            p0 = *(const f32x4*)ap;
            p1 = *(const f32x4*)(ap + 4);
        }
        u16x8 kvv[2][2];
#pragma unroll
        for (int n_ = 0; n_ < 2; ++n_) {
            const int jg = j0 + n_ * 16 + l15;
#pragma unroll
            for (int m_ = 0; m_ < 2; ++m_)
                kvv[n_][m_] = *(const u16x8*)(kvb + ((size_t)jg * D + w * 32 + m_ * 16 + lk * 4) * 2);
        }

        // ---- GEMM1 (weights in regs): acc[m_][n_] over both 16-j halves ----
        f32x4 acc1[2][2], acc2[2][2];
#pragma unroll
        for (int m_ = 0; m_ < 2; ++m_) {
            const f32x4 i1 = (f32x4){b1c[m_ * 4 + 0], b1c[m_ * 4 + 1], b1c[m_ * 4 + 2], b1c[m_ * 4 + 3]};
            const f32x4 i2 = (f32x4){b2c[m_ * 4 + 0], b2c[m_ * 4 + 1], b2c[m_ * 4 + 2], b2c[m_ * 4 + 3]};
#pragma unroll
            for (int n_ = 0; n_ < 2; ++n_) { acc1[m_][n_] = i1; acc2[m_][n_] = i2; }
        }
#pragma unroll
        for (int ks = 0; ks < 4; ++ks) {
            short8 bfrg[2];
#pragma unroll
            for (int n_ = 0; n_ < 2; ++n_) {
                const int jrow = n_ * 16 + l15;
                const unsigned baddr = ((unsigned)(jrow * 256 + (ks * 32 + lk * 8) * 2))
                                       ^ ((unsigned)(jrow & 7) << 4);
                bfrg[n_] = *(const short8*)((const char*)ab + baddr);
            }
#pragma unroll
            for (int m_ = 0; m_ < 2; ++m_)
#pragma unroll
                for (int n_ = 0; n_ < 2; ++n_) {
                    acc1[m_][n_] = mfma16(waf[ks][m_], bfrg[n_], acc1[m_][n_]);
                    acc2[m_][n_] = mfma16(wmf[ks][m_], bfrg[n_], acc2[m_][n_]);
                }
        }

        // ---- phase B (in-register): Y, h->LDS, softmax accumulation ----
#pragma unroll
        for (int n_ = 0; n_ < 2; ++n_) {
            const int jrow = n_ * 16 + l15;
#pragma unroll
            for (int m_ = 0; m_ < 2; ++m_) {
                u16x4 hp;
#pragma unroll
                for (int r = 0; r < 4; ++r) {
                    const int fi = m_ * 4 + r;
                    const float kf = bf2f(kvv[n_][m_][2 * r]);
                    const float vf = bf2f(kvv[n_][m_][2 * r + 1]);
                    const float yv = qs[fi] * kf * acc1[m_][n_][r] + acc2[m_][n_][r];
                    hp[r] = f2bf(e1c[fi] + e2c[fi] * yv);
                    const float ev = __expf(yv);
                    sm_l[fi] += ev;
                    sm_a[fi] += ev * vf;
                }
                const unsigned haddr = ((unsigned)(jrow * 512 + (w * 32 + m_ * 16 + lk * 4) * 2))
                                       ^ ((unsigned)(jrow & 7) << 4);
                *(u16x4*)((char*)hw + haddr) = hp;
            }
        }

        // ---- write prefetched a-tile to the other buffer ----
        if (t < 7) {
            u16x8 pk;
            pk.s0 = f2bf(p0.x); pk.s1 = f2bf(p0.y); pk.s2 = f2bf(p0.z); pk.s3 = f2bf(p0.w);
            pk.s4 = f2bf(p1.x); pk.s5 = f2bf(p1.y); pk.s6 = f2bf(p1.z); pk.s7 = f2bf(p1.w);
            *(u16x8*)((char*)abuf[(t + 1) & 1] + saddr) = pk;
        }
        __syncthreads();   // h ready; next a-tile ready; abuf[t&1] reads done

        // ---- GEMM2 (weights in regs): ahat^T[e][j] = W2T . h^T (+bias) ----
        f32x4 accO[2];
        accO[0] = bias2; accO[1] = bias2;
#pragma unroll
        for (int ks = 0; ks < 8; ++ks) {
            const int foff = ks * 32 + lk * 8;
#pragma unroll
            for (int n2 = 0; n2 < 2; ++n2) {
                const int jrow = n2 * 16 + l15;
                const unsigned haddr = ((unsigned)(jrow * 512 + foff * 2))
                                       ^ ((unsigned)(jrow & 7) << 4);
                const short8 hf = *(const short8*)((const char*)hw + haddr);
                accO[n2] = mfma16(w2f[ks], hf, accO[n2]);
            }
        }
        {
            const int eb = w * 16 + lk * 4;
#pragma unroll
            for (int n2 = 0; n2 < 2; ++n2) {
                const int jg2 = j0 + n2 * 16 + l15;
                *(f32x4*)(ahatp + (size_t)jg2 * E + eb) = accO[n2];
            }
        }
    }

    // ---- merge softmax partials across l15 (sum over j-columns) ----
#pragma unroll
    for (int st = 1; st <= 8; st <<= 1) {
#pragma unroll
        for (int fi = 0; fi < 8; ++fi) {
            sm_l[fi] += __shfl_xor(sm_l[fi], st, 64);
            sm_a[fi] += __shfl_xor(sm_a[fi], st, 64);
        }
    }
    if (l15 == 0) {
#pragma unroll
        for (int m_ = 0; m_ < 2; ++m_)
#pragma unroll
            for (int r = 0; r < 4; ++r) {
                const int fi = m_ * 4 + r;
                const int f  = w * 32 + m_ * 16 + lk * 4 + r;
                wV[(size_t)bi * D + f] = sm_a[fi] / sm_l[fi];
            }
    }
}

// ---------------------------------------------------------------------------
// POST (fused): xhat (blocks 0..63) + za_reduce (blocks 64..65). 256 thr.
// ---------------------------------------------------------------------------
__global__ __launch_bounds__(256) void post_kernel(
        const float* __restrict__ wV,
        const float* __restrict__ yx1, const float* __restrict__ yx2,
        const float* __restrict__ W, const float* __restrict__ B,
        const float* __restrict__ psum, const float* __restrict__ psumsq,
        const float* __restrict__ pmin, const float* __restrict__ pmax,
        float* __restrict__ xhat, float* __restrict__ za) {
    const int blk = blockIdx.x;
    const int tid = threadIdx.x;
    __shared__ float smem[2048];

    if (blk < 64) {
        // ---- xhat ----
        float (*xr)[D] = (float(*)[D])smem;
#pragma unroll
        for (int r = 0; r < 8; ++r) {
            const int row = blk * 8 + r;
            const int b = row >> 8;
            xr[r][tid] = yx1[b * D + tid] + (yx2[b * D + tid] + 1.f) * wV[(size_t)row * D + tid];
        }
        __syncthreads();
        float acc[8];
        const float bb = B[tid];
#pragma unroll
        for (int r = 0; r < 8; ++r) acc[r] = bb;
#pragma unroll 4
        for (int k = 0; k < D; ++k) {
            const float w = W[k * D + tid];
#pragma unroll
            for (int r = 0; r < 8; ++r) acc[r] += xr[r][k] * w;
        }
#pragma unroll
        for (int r = 0; r < 8; ++r)
            xhat[(size_t)(blk * 8 + r) * D + tid] = acc[r];
    } else {
        // ---- za_reduce : b = blk-64; 2-way i-split ----
        const int b = blk - 64;
        const int feat = tid & 127;
        const int g = tid >> 7;       // 0..1
        float s = 0.f, ss = 0.f, mn = INFINITY, mx = -INFINITY;
#pragma unroll 4
        for (int c = g * 128; c < g * 128 + 128; ++c) {
            const int o = (b * 256 + c) * E + feat;
            s += psum[o]; ss += psumsq[o];
            mn = fminf(mn, pmin[o]); mx = fmaxf(mx, pmax[o]);
        }
        smem[0 * 256 + g * 128 + feat] = s;
        smem[1 * 256 + g * 128 + feat] = ss;
        smem[2 * 256 + g * 128 + feat] = mn;
        smem[3 * 256 + g * 128 + feat] = mx;
        __syncthreads();
        if (g == 0) {
            s += smem[0 * 256 + 128 + feat]; ss += smem[1 * 256 + 128 + feat];
            mn = fminf(mn, smem[2 * 256 + 128 + feat]);
            mx = fmaxf(mx, smem[3 * 256 + 128 + feat]);
            const float M = 65536.f;
            const float mean = s / M;
            const float var  = (ss - s * s / M) / (M - 1.f);
            za[b * 512 + feat]       = mean;
            za[b * 512 + 128 + feat] = mn;
            za[b * 512 + 256 + feat] = mx;
            za[b * 512 + 384 + feat] = sqrtf(fmaxf(var, 0.f));
        }
    }
}

// ---------------------------------------------------------------------------
// yhat MLP — 512 threads, 4-way k-split + LDS reduce
// ---------------------------------------------------------------------------
__global__ void yhat_kernel(const float* __restrict__ y,
                            const float* __restrict__ za, const float* __restrict__ zx,
                            const float* __restrict__ yyw, const float* __restrict__ yyb,
                            const float* __restrict__ xyw, const float* __restrict__ xyb,
                            const float* __restrict__ ayw, const float* __restrict__ ayb,
                            const float* __restrict__ w1, const float* __restrict__ b1,
                            const float* __restrict__ w2, const float* __restrict__ b2,
                            float* __restrict__ out) {
    const int b = blockIdx.x;
    const int tid = threadIdx.x;
    const int o = tid & 127;
    const int q = tid >> 7;
    __shared__ float zy[1664];           // [y(128) | za(512) | zx(1024)]
    for (int idx = tid; idx < 1664; idx += 512) {
        float v;
        if (idx < 128)      v = y[b * YD + idx];
        else if (idx < 640) v = za[b * 512 + idx - 128];
        else                v = zx[b * 1024 + idx - 640];
        zy[idx] = v;
    }
    __syncthreads();
    float p = 0.f;
    if (q == 0) {
#pragma unroll 4
        for (int k = 0; k < 128; ++k) p += zy[k] * yyw[k * YD + o];
#pragma unroll 4
        for (int k = 0; k < 128; ++k) p += zy[128 + k] * ayw[k * YD + o];
    } else if (q == 1) {
#pragma unroll 4
        for (int k = 128; k < 512; ++k) p += zy[128 + k] * ayw[k * YD + o];
    } else if (q == 2) {
#pragma unroll 4
        for (int k = 0; k < 512; ++k) p += zy[640 + k] * xyw[k * YD + o];
    } else {
#pragma unroll 4
        for (int k = 512; k < 1024; ++k) p += zy[640 + k] * xyw[k * YD + o];
    }
    __shared__ float red[4][128];
    __shared__ float h1s[128], h2s[128];
    red[q][o] = p;
    __syncthreads();
    if (tid < 128) {
        h1s[o] = yyb[o] + xyb[o] + ayb[o] + red[0][o] + red[1][o] + red[2][o] + red[3][o];
    }
    __syncthreads();
    float p2 = 0.f;
#pragma unroll 4
    for (int k = q * 32; k < q * 32 + 32; ++k) p2 += h1s[k] * w1[k * YD + o];
    red[q][o] = p2;
    __syncthreads();
    if (tid < 128) h2s[o] = fmaxf(b1[o] + red[0][o] + red[1][o] + red[2][o] + red[3][o], 0.f);
    __syncthreads();
    float p3 = 0.f;
#pragma unroll 4
    for (int k = q * 32; k < q * 32 + 32; ++k) p3 += h2s[k] * w2[k * YD + o];
    red[q][o] = p3;
    __syncthreads();
    if (tid < 128) out[b * YD + o] = b2[o] + red[0][o] + red[1][o] + red[2][o] + red[3][o];
}

// ---------------------------------------------------------------------------
extern "C" void kernel_launch(void* const* d_in, const int* in_sizes, int n_in,
                              void* d_out, int out_size, void* d_ws, size_t ws_size,
                              hipStream_t stream) {
    const float* x         = (const float*)d_in[0];
    const float* a         = (const float*)d_in[1];
    const float* y         = (const float*)d_in[2];
    const float* qw        = (const float*)d_in[3];  const float* qb        = (const float*)d_in[4];
    const float* kw        = (const float*)d_in[5];  const float* kb        = (const float*)d_in[6];
    const float* vw        = (const float*)d_in[7];  const float* vb        = (const float*)d_in[8];
    const float* a2x_add_w = (const float*)d_in[9];  const float* a2x_add_b = (const float*)d_in[10];
    const float* a2x_mul_w = (const float*)d_in[11]; const float* a2x_mul_b = (const float*)d_in[12];
    const float* y2e_mul_w = (const float*)d_in[13]; const float* y2e_mul_b = (const float*)d_in[14];
    const float* y2e_add_w = (const float*)d_in[15]; const float* y2e_add_b = (const float*)d_in[16];
    const float* y2x_mul_w = (const float*)d_in[17]; const float* y2x_mul_b = (const float*)d_in[18];
    const float* y2x_add_w = (const float*)d_in[19]; const float* y2x_add_b = (const float*)d_in[20];
    const float* y_y_w     = (const float*)d_in[21]; const float* y_y_b     = (const float*)d_in[22];
    const float* x_y_w     = (const float*)d_in[23]; const float* x_y_b     = (const float*)d_in[24];
    const float* a_y_w     = (const float*)d_in[25]; const float* a_y_b     = (const float*)d_in[26];
    const float* x_out_w   = (const float*)d_in[27]; const float* x_out_b   = (const float*)d_in[28];
    const float* a_out_w   = (const float*)d_in[29]; const float* a_out_b   = (const float*)d_in[30];
    const float* y_out1_w  = (const float*)d_in[31]; const float* y_out1_b  = (const float*)d_in[32];
    const float* y_out2_w  = (const float*)d_in[33]; const float* y_out2_b  = (const float*)d_in[34];

    float* ws = (float*)d_ws;
    float* Q      = ws;                                   // 131072
    unsigned short* kvJ = (unsigned short*)(ws + 131072); // 262144 u16 = 131072 f
    float* wV     = ws + 262144;                          // 131072
    float* ye1    = ws + 393216;   // 512
    float* ye2    = ws + 393728;
    float* yx1    = ws + 394240;
    float* yx2    = ws + 394752;
    float* psum   = ws + 395264;   // 65536
    float* psumsq = ws + 460800;
    float* pminb  = ws + 526336;
    float* pmaxb  = ws + 591872;
    float* za     = ws + 657408;   // 1024
    float* zx     = ws + 658432;   // 2048
    unsigned short* WaddT = (unsigned short*)(ws + 660480);  // 32768 u16
    unsigned short* WmulT = (unsigned short*)(ws + 676864);
    unsigned short* W2T   = (unsigned short*)(ws + 693248);

    float* xhat = (float*)d_out;
    float* ahat = (float*)d_out + 131072;
    float* yhat = (float*)d_out + 16908288;

    prep_kernel<<<1112, 256, 0, stream>>>(
        x, a, y, qw, qb, kw, kb, vw, vb,
        a2x_add_w, a2x_mul_w, a_out_w,
        y2e_add_w, y2e_add_b, y2e_mul_w, y2e_mul_b,
        y2x_add_w, y2x_add_b, y2x_mul_w, y2x_mul_b,
        Q, kvJ, WaddT, WmulT, W2T,
        ye1, ye2, yx1, yx2,
        psum, psumsq, pminb, pmaxb, zx);
    main_kernel<<<512, 512, 0, stream>>>(a, WaddT, a2x_add_b, WmulT, a2x_mul_b,
                                         W2T, a_out_b, Q, kvJ, ye1, ye2, ahat, wV);
    post_kernel<<<66, 256, 0, stream>>>(wV, yx1, yx2, x_out_w, x_out_b,
                                        psum, psumsq, pminb, pmaxb, xhat, za);
    yhat_kernel<<<2, 512, 0, stream>>>(y, za, zx, y_y_w, y_y_b, x_y_w, x_y_b, a_y_w, a_y_b,
                                       y_out1_w, y_out1_b, y_out2_w, y_out2_b, yhat);
}

// Round 10
// 115.836 us; speedup vs baseline: 2.5281x; 1.3183x over previous
//
#include <hip/hip_runtime.h>
#include <hip/hip_bf16.h>
#include <cstddef>

// Problem constants
constexpr int BS = 2;
constexpr int N  = 256;
constexpr int D  = 256;   // NH_N
constexpr int E  = 128;   // NH_E
constexpr int YD = 128;   // NH_Y
constexpr float RSQRT_F = 0.17677669529663687f;  // 1/sqrt(32)

typedef __attribute__((ext_vector_type(8))) short     short8;
typedef __attribute__((ext_vector_type(4))) float     f32x4;
typedef __attribute__((ext_vector_type(4))) unsigned short u16x4;
typedef __attribute__((ext_vector_type(8))) unsigned short u16x8;

__device__ __forceinline__ unsigned short f2bf(float x) {
    unsigned u = __float_as_uint(x);
    unsigned r = (u + 0x7fffu + ((u >> 16) & 1u)) >> 16;   // RNE
    return (unsigned short)r;
}
__device__ __forceinline__ float bf2f(unsigned short h) {
    return __uint_as_float(((unsigned)h) << 16);
}
__device__ __forceinline__ f32x4 mfma16(short8 a, short8 b, f32x4 c) {
    return __builtin_amdgcn_mfma_f32_16x16x32_bf16(a, b, c, 0, 0, 0);
}

// ---------------------------------------------------------------------------
// PREP (fused): qkv + wt + ymap + zx + za_part(vectorized)
// grid 1112 x 256
// ---------------------------------------------------------------------------
__global__ __launch_bounds__(256) void prep_kernel(
        const float* __restrict__ x, const float* __restrict__ a,
        const float* __restrict__ y,
        const float* __restrict__ qw, const float* __restrict__ qb,
        const float* __restrict__ kw, const float* __restrict__ kb,
        const float* __restrict__ vw, const float* __restrict__ vb,
        const float* __restrict__ Wadd, const float* __restrict__ Wmul,
        const float* __restrict__ W2,
        const float* __restrict__ we_add, const float* __restrict__ be_add,
        const float* __restrict__ we_mul, const float* __restrict__ be_mul,
        const float* __restrict__ wx_add, const float* __restrict__ bx_add,
        const float* __restrict__ wx_mul, const float* __restrict__ bx_mul,
        float* __restrict__ Q, unsigned short* __restrict__ kvJ,
        unsigned short* __restrict__ WaddT, unsigned short* __restrict__ WmulT,
        unsigned short* __restrict__ W2T,
        float* __restrict__ ye1, float* __restrict__ ye2,
        float* __restrict__ yx1, float* __restrict__ yx2,
        float* __restrict__ psum, float* __restrict__ psumsq,
        float* __restrict__ pmin, float* __restrict__ pmax,
        float* __restrict__ zx) {
    const int blk = blockIdx.x;
    const int tid = threadIdx.x;
    __shared__ float smem[4096];

    if (blk < 192) {
        // ---- qkv ----
        const int m  = blk >> 6;
        const int rg = blk & 63;
        const float* W = (m == 0) ? qw : (m == 1) ? kw : vw;
        const float* B = (m == 0) ? qb : (m == 1) ? kb : vb;
        float (*xs)[D] = (float(*)[D])smem;
#pragma unroll
        for (int r = 0; r < 8; ++r)
            xs[r][tid] = x[(size_t)(rg * 8 + r) * D + tid];
        __syncthreads();
        float acc[8];
        const float bb = B[tid];
#pragma unroll
        for (int r = 0; r < 8; ++r) acc[r] = bb;
#pragma unroll 4
        for (int k = 0; k < D; ++k) {
            const float w = W[k * D + tid];
#pragma unroll
            for (int r = 0; r < 8; ++r) acc[r] += xs[r][k] * w;
        }
#pragma unroll
        for (int r = 0; r < 8; ++r) {
            const int row = rg * 8 + r;
            if (m == 0) Q[(size_t)row * D + tid] = acc[r];
            else        kvJ[((size_t)row * D + tid) * 2 + (m - 1)] = f2bf(acc[r]);
        }
    } else if (blk < 576) {
        // ---- wt ----
        int idx = (blk - 192) * 256 + tid;
        int s = idx >> 15;
        int k = idx & 32767;
        if (s == 0)      { int f = k >> 7, e = k & 127; WaddT[k] = f2bf(Wadd[e * 256 + f]); }
        else if (s == 1) { int f = k >> 7, e = k & 127; WmulT[k] = f2bf(Wmul[e * 256 + f]); }
        else             { int f = k & 255, e = k >> 8; W2T[k]   = f2bf(W2[f * 128 + e]); }
    } else if (blk < 584) {
        // ---- ymap ----
        const int bb = (blk - 576) >> 2;
        const int m  = (blk - 576) & 3;
        const float* W; const float* B; float* O;
        switch (m) {
            case 0:  W = we_add; B = be_add; O = ye1; break;
            case 1:  W = we_mul; B = be_mul; O = ye2; break;
            case 2:  W = wx_add; B = bx_add; O = yx1; break;
            default: W = wx_mul; B = bx_mul; O = yx2; break;
        }
        float acc = B[tid];
#pragma unroll 4
        for (int k = 0; k < YD; ++k)
            acc += y[bb * YD + k] * W[k * D + tid];
        O[bb * D + tid] = acc;
    } else if (blk < 600) {
        // ---- zx : block = (b, f-chunk of 32); 8-way i-split ----
        const int bb = (blk - 584) >> 3;
        const int fc = (blk - 584) & 7;
        const int fl = tid & 31;
        const int ig = tid >> 5;
        const int f  = fc * 32 + fl;
        float s = 0.f, ss = 0.f, mn = INFINITY, mx = -INFINITY;
#pragma unroll 4
        for (int i = ig * 32; i < ig * 32 + 32; ++i) {
            const float v = x[((size_t)bb * N + i) * D + f];
            s += v; ss += v * v; mn = fminf(mn, v); mx = fmaxf(mx, v);
        }
        smem[0 * 256 + ig * 32 + fl] = s;
        smem[1 * 256 + ig * 32 + fl] = ss;
        smem[2 * 256 + ig * 32 + fl] = mn;
        smem[3 * 256 + ig * 32 + fl] = mx;
        __syncthreads();
        if (ig == 0) {
#pragma unroll
            for (int gg = 1; gg < 8; ++gg) {
                s += smem[0 * 256 + gg * 32 + fl]; ss += smem[1 * 256 + gg * 32 + fl];
                mn = fminf(mn, smem[2 * 256 + gg * 32 + fl]);
                mx = fmaxf(mx, smem[3 * 256 + gg * 32 + fl]);
            }
            const float M = 256.f;
            const float mean = s / M;
            const float var  = (ss - s * s / M) / (M - 1.f);
            zx[bb * 1024 + f]       = mean;
            zx[bb * 1024 + 256 + f] = mn;
            zx[bb * 1024 + 512 + f] = mx;
            zx[bb * 1024 + 768 + f] = sqrtf(fmaxf(var, 0.f));
        }
    } else {
        // ---- za_part (vectorized): block = (b,i); f32x4 loads ----
        const int bi2 = blk - 600;            // b*256 + i
        const int te  = tid & 31;             // e-quad index
        const int tj  = tid >> 5;             // 0..7
        const float* base = a + (size_t)bi2 * N * E + te * 4;
        f32x4 s4  = (f32x4){0.f, 0.f, 0.f, 0.f};
        f32x4 ss4 = (f32x4){0.f, 0.f, 0.f, 0.f};
        f32x4 mn4 = (f32x4){INFINITY, INFINITY, INFINITY, INFINITY};
        f32x4 mx4 = (f32x4){-INFINITY, -INFINITY, -INFINITY, -INFINITY};
#pragma unroll 4
        for (int j = tj * 32; j < tj * 32 + 32; ++j) {
            const f32x4 v = *(const f32x4*)(base + (size_t)j * E);
            s4 += v;
            ss4.x = fmaf(v.x, v.x, ss4.x); ss4.y = fmaf(v.y, v.y, ss4.y);
            ss4.z = fmaf(v.z, v.z, ss4.z); ss4.w = fmaf(v.w, v.w, ss4.w);
            mn4.x = fminf(mn4.x, v.x); mn4.y = fminf(mn4.y, v.y);
            mn4.z = fminf(mn4.z, v.z); mn4.w = fminf(mn4.w, v.w);
            mx4.x = fmaxf(mx4.x, v.x); mx4.y = fmaxf(mx4.y, v.y);
            mx4.z = fmaxf(mx4.z, v.z); mx4.w = fmaxf(mx4.w, v.w);
        }
        *(f32x4*)(smem + (0 * 8 + tj) * 128 + te * 4) = s4;
        *(f32x4*)(smem + (1 * 8 + tj) * 128 + te * 4) = ss4;
        *(f32x4*)(smem + (2 * 8 + tj) * 128 + te * 4) = mn4;
        *(f32x4*)(smem + (3 * 8 + tj) * 128 + te * 4) = mx4;
        __syncthreads();
        if (tid < 128) {
            float s = 0.f, ss = 0.f, mn = INFINITY, mx = -INFINITY;
#pragma unroll
            for (int g = 0; g < 8; ++g) {
                s  += smem[(0 * 8 + g) * 128 + tid];
                ss += smem[(1 * 8 + g) * 128 + tid];
                mn = fminf(mn, smem[(2 * 8 + g) * 128 + tid]);
                mx = fmaxf(mx, smem[(3 * 8 + g) * 128 + tid]);
            }
            const int o = bi2 * E + tid;
            psum[o] = s; psumsq[o] = ss; pmin[o] = mn; pmax[o] = mx;
        }
    }
}

// ---------------------------------------------------------------------------
// MAIN (r6-proven): block = one (b,i). 8 waves, (512,1). 8 passes x 32 j.
// ALL weight fragments hoisted (waf/wmf/w2f = 96 VGPR). XCD-swizzled bi.
// ---------------------------------------------------------------------------
__global__ __launch_bounds__(512, 1) void main_kernel(
        const float* __restrict__ a,
        const unsigned short* __restrict__ WaddT, const float* __restrict__ Badd,
        const unsigned short* __restrict__ WmulT, const float* __restrict__ Bmul,
        const unsigned short* __restrict__ W2T,  const float* __restrict__ AoutB,
        const float* __restrict__ Q, const unsigned short* __restrict__ kvJ,
        const float* __restrict__ ye1, const float* __restrict__ ye2,
        float* __restrict__ ahat, float* __restrict__ wV) {
    // XCD-aware bijective swizzle (512 % 8 == 0)
    const int bi = ((blockIdx.x & 7) << 6) | (blockIdx.x >> 3);
    const int b  = bi >> 8;
    const int tid  = threadIdx.x;
    const int lane = tid & 63;
    const int w    = tid >> 6;         // wave id 0..7
    const int l15  = lane & 15;
    const int lk   = lane >> 4;        // 0..3

    __shared__ unsigned short abuf[2][32 * 128];   // 2 x 8 KB  a-tile bf16 (swizzled)
    __shared__ unsigned short hbuf[2][32 * 256];   // 2 x 16 KB h bf16 (swizzled)

    const float* arow = a + (size_t)bi * (N * E);
    float* ahatp      = ahat + (size_t)bi * (N * E);
    const unsigned short* kvb = kvJ + (size_t)b * N * D * 2;

    // ---- hoist ALL weight fragments (pass-invariant) into registers ----
    short8 waf[4][2], wmf[4][2], w2f[8];
#pragma unroll
    for (int ks = 0; ks < 4; ++ks)
#pragma unroll
        for (int m_ = 0; m_ < 2; ++m_) {
            const int frow = w * 32 + m_ * 16 + l15;
            waf[ks][m_] = *(const short8*)(WaddT + frow * 128 + ks * 32 + lk * 8);
            wmf[ks][m_] = *(const short8*)(WmulT + frow * 128 + ks * 32 + lk * 8);
        }
#pragma unroll
    for (int ks = 0; ks < 8; ++ks)
        w2f[ks] = *(const short8*)(W2T + (w * 16 + l15) * 256 + ks * 32 + lk * 8);

    // hoisted per-f constants: f = w*32 + m_*16 + lk*4 + r  (fi = m_*4+r)
    float qs[8], e1c[8], e2c[8], b1c[8], b2c[8];
#pragma unroll
    for (int m_ = 0; m_ < 2; ++m_) {
        const int f0 = w * 32 + m_ * 16 + lk * 4;
        const f32x4 qv = *(const f32x4*)(Q + (size_t)bi * D + f0);
        const f32x4 a1 = *(const f32x4*)(ye1 + b * D + f0);
        const f32x4 a2 = *(const f32x4*)(ye2 + b * D + f0);
        const f32x4 bb1 = *(const f32x4*)(Badd + f0);
        const f32x4 bb2 = *(const f32x4*)(Bmul + f0);
#pragma unroll
        for (int r = 0; r < 4; ++r) {
            const int fi = m_ * 4 + r;
            qs[fi]  = qv[r] * RSQRT_F;
            e1c[fi] = a1[r];
            e2c[fi] = a2[r] + 1.f;
            b1c[fi] = bb1[r] + 1.f;   // (a1 + 1) bias
            b2c[fi] = bb2[r];
        }
    }
    const f32x4 bias2 = *(const f32x4*)(AoutB + w * 16 + lk * 4);

    // softmax accumulators (no max tracking: |Y| <~ 2.5 by construction)
    float sm_l[8], sm_a[8];
#pragma unroll
    for (int q = 0; q < 8; ++q) { sm_l[q] = 0.f; sm_a[q] = 0.f; }

    const int sjl = tid >> 4;          // staging row 0..31
    const int seq = tid & 15;          // staging 8-float chunk
    const unsigned saddr = ((unsigned)(sjl * 256 + seq * 16)) ^ ((unsigned)(sjl & 7) << 4);

    // prologue: stage pass 0
    {
        const float* ap = arow + (size_t)sjl * E + seq * 8;
        const f32x4 v0 = *(const f32x4*)ap;
        const f32x4 v1 = *(const f32x4*)(ap + 4);
        u16x8 pk;
        pk.s0 = f2bf(v0.x); pk.s1 = f2bf(v0.y); pk.s2 = f2bf(v0.z); pk.s3 = f2bf(v0.w);
        pk.s4 = f2bf(v1.x); pk.s5 = f2bf(v1.y); pk.s6 = f2bf(v1.z); pk.s7 = f2bf(v1.w);
        *(u16x8*)((char*)abuf[0] + saddr) = pk;
    }
    __syncthreads();

    for (int t = 0; t < 8; ++t) {
        const int j0 = t * 32;
        const unsigned short* ab = abuf[t & 1];
        unsigned short* hw = hbuf[t & 1];

        // issue global prefetches early: next a-tile (HBM) + this pass's kv (L2)
        f32x4 p0, p1;
        if (t < 7) {
            const float* ap = arow + (size_t)(j0 + 32 + sjl) * E + seq * 8;
            p0 = *(const f32x4*)ap;
            p1 = *(const f32x4*)(ap + 4);
        }
        u16x8 kvv[2][2];
#pragma unroll
        for (int n_ = 0; n_ < 2; ++n_) {
            const int jg = j0 + n_ * 16 + l15;
#pragma unroll
            for (int m_ = 0; m_ < 2; ++m_)
                kvv[n_][m_] = *(const u16x8*)(kvb + ((size_t)jg * D + w * 32 + m_ * 16 + lk * 4) * 2);
        }

        // ---- GEMM1 (weights in regs) ----
        f32x4 acc1[2][2], acc2[2][2];
#pragma unroll
        for (int m_ = 0; m_ < 2; ++m_) {
            const f32x4 i1 = (f32x4){b1c[m_ * 4 + 0], b1c[m_ * 4 + 1], b1c[m_ * 4 + 2], b1c[m_ * 4 + 3]};
            const f32x4 i2 = (f32x4){b2c[m_ * 4 + 0], b2c[m_ * 4 + 1], b2c[m_ * 4 + 2], b2c[m_ * 4 + 3]};
#pragma unroll
            for (int n_ = 0; n_ < 2; ++n_) { acc1[m_][n_] = i1; acc2[m_][n_] = i2; }
        }
#pragma unroll
        for (int ks = 0; ks < 4; ++ks) {
            short8 bfrg[2];
#pragma unroll
            for (int n_ = 0; n_ < 2; ++n_) {
                const int jrow = n_ * 16 + l15;
                const unsigned baddr = ((unsigned)(jrow * 256 + (ks * 32 + lk * 8) * 2))
                                       ^ ((unsigned)(jrow & 7) << 4);
                bfrg[n_] = *(const short8*)((const char*)ab + baddr);
            }
#pragma unroll
            for (int m_ = 0; m_ < 2; ++m_)
#pragma unroll
                for (int n_ = 0; n_ < 2; ++n_) {
                    acc1[m_][n_] = mfma16(waf[ks][m_], bfrg[n_], acc1[m_][n_]);
                    acc2[m_][n_] = mfma16(wmf[ks][m_], bfrg[n_], acc2[m_][n_]);
                }
        }

        // ---- phase B (in-register): Y, h->LDS, softmax accumulation ----
#pragma unroll
        for (int n_ = 0; n_ < 2; ++n_) {
            const int jrow = n_ * 16 + l15;
#pragma unroll
            for (int m_ = 0; m_ < 2; ++m_) {
                u16x4 hp;
#pragma unroll
                for (int r = 0; r < 4; ++r) {
                    const int fi = m_ * 4 + r;
                    const float kf = bf2f(kvv[n_][m_][2 * r]);
                    const float vf = bf2f(kvv[n_][m_][2 * r + 1]);
                    const float yv = qs[fi] * kf * acc1[m_][n_][r] + acc2[m_][n_][r];
                    hp[r] = f2bf(e1c[fi] + e2c[fi] * yv);
                    const float ev = __expf(yv);
                    sm_l[fi] += ev;
                    sm_a[fi] += ev * vf;
                }
                const unsigned haddr = ((unsigned)(jrow * 512 + (w * 32 + m_ * 16 + lk * 4) * 2))
                                       ^ ((unsigned)(jrow & 7) << 4);
                *(u16x4*)((char*)hw + haddr) = hp;
            }
        }

        // ---- write prefetched a-tile to the other buffer ----
        if (t < 7) {
            u16x8 pk;
            pk.s0 = f2bf(p0.x); pk.s1 = f2bf(p0.y); pk.s2 = f2bf(p0.z); pk.s3 = f2bf(p0.w);
            pk.s4 = f2bf(p1.x); pk.s5 = f2bf(p1.y); pk.s6 = f2bf(p1.z); pk.s7 = f2bf(p1.w);
            *(u16x8*)((char*)abuf[(t + 1) & 1] + saddr) = pk;
        }
        __syncthreads();   // h ready; next a-tile ready; abuf[t&1] reads done

        // ---- GEMM2 (weights in regs) ----
        f32x4 accO[2];
        accO[0] = bias2; accO[1] = bias2;
#pragma unroll
        for (int ks = 0; ks < 8; ++ks) {
            const int foff = ks * 32 + lk * 8;
#pragma unroll
            for (int n2 = 0; n2 < 2; ++n2) {
                const int jrow = n2 * 16 + l15;
                const unsigned haddr = ((unsigned)(jrow * 512 + foff * 2))
                                       ^ ((unsigned)(jrow & 7) << 4);
                const short8 hf = *(const short8*)((const char*)hw + haddr);
                accO[n2] = mfma16(w2f[ks], hf, accO[n2]);
            }
        }
        {
            const int eb = w * 16 + lk * 4;
#pragma unroll
            for (int n2 = 0; n2 < 2; ++n2) {
                const int jg2 = j0 + n2 * 16 + l15;
                *(f32x4*)(ahatp + (size_t)jg2 * E + eb) = accO[n2];
            }
        }
    }

    // ---- merge softmax partials across l15 (sum over j-columns) ----
#pragma unroll
    for (int st = 1; st <= 8; st <<= 1) {
#pragma unroll
        for (int fi = 0; fi < 8; ++fi) {
            sm_l[fi] += __shfl_xor(sm_l[fi], st, 64);
            sm_a[fi] += __shfl_xor(sm_a[fi], st, 64);
        }
    }
    if (l15 == 0) {
#pragma unroll
        for (int m_ = 0; m_ < 2; ++m_)
#pragma unroll
            for (int r = 0; r < 4; ++r) {
                const int fi = m_ * 4 + r;
                const int f  = w * 32 + m_ * 16 + lk * 4 + r;
                wV[(size_t)bi * D + f] = sm_a[fi] / sm_l[fi];
            }
    }
}

// ---------------------------------------------------------------------------
// POST (fused): xhat (blocks 0..63) + za_reduce (blocks 64..65). 256 thr.
// ---------------------------------------------------------------------------
__global__ __launch_bounds__(256) void post_kernel(
        const float* __restrict__ wV,
        const float* __restrict__ yx1, const float* __restrict__ yx2,
        const float* __restrict__ W, const float* __restrict__ B,
        const float* __restrict__ psum, const float* __restrict__ psumsq,
        const float* __restrict__ pmin, const float* __restrict__ pmax,
        float* __restrict__ xhat, float* __restrict__ za) {
    const int blk = blockIdx.x;
    const int tid = threadIdx.x;
    __shared__ float smem[2048];

    if (blk < 64) {
        // ---- xhat ----
        float (*xr)[D] = (float(*)[D])smem;
#pragma unroll
        for (int r = 0; r < 8; ++r) {
            const int row = blk * 8 + r;
            const int b = row >> 8;
            xr[r][tid] = yx1[b * D + tid] + (yx2[b * D + tid] + 1.f) * wV[(size_t)row * D + tid];
        }
        __syncthreads();
        float acc[8];
        const float bb = B[tid];
#pragma unroll
        for (int r = 0; r < 8; ++r) acc[r] = bb;
#pragma unroll 4
        for (int k = 0; k < D; ++k) {
            const float w = W[k * D + tid];
#pragma unroll
            for (int r = 0; r < 8; ++r) acc[r] += xr[r][k] * w;
        }
#pragma unroll
        for (int r = 0; r < 8; ++r)
            xhat[(size_t)(blk * 8 + r) * D + tid] = acc[r];
    } else {
        // ---- za_reduce : b = blk-64; 2-way i-split ----
        const int b = blk - 64;
        const int feat = tid & 127;
        const int g = tid >> 7;       // 0..1
        float s = 0.f, ss = 0.f, mn = INFINITY, mx = -INFINITY;
#pragma unroll 4
        for (int c = g * 128; c < g * 128 + 128; ++c) {
            const int o = (b * 256 + c) * E + feat;
            s += psum[o]; ss += psumsq[o];
            mn = fminf(mn, pmin[o]); mx = fmaxf(mx, pmax[o]);
        }
        smem[0 * 256 + g * 128 + feat] = s;
        smem[1 * 256 + g * 128 + feat] = ss;
        smem[2 * 256 + g * 128 + feat] = mn;
        smem[3 * 256 + g * 128 + feat] = mx;
        __syncthreads();
        if (g == 0) {
            s += smem[0 * 256 + 128 + feat]; ss += smem[1 * 256 + 128 + feat];
            mn = fminf(mn, smem[2 * 256 + 128 + feat]);
            mx = fmaxf(mx, smem[3 * 256 + 128 + feat]);
            const float M = 65536.f;
            const float mean = s / M;
            const float var  = (ss - s * s / M) / (M - 1.f);
            za[b * 512 + feat]       = mean;
            za[b * 512 + 128 + feat] = mn;
            za[b * 512 + 256 + feat] = mx;
            za[b * 512 + 384 + feat] = sqrtf(fmaxf(var, 0.f));
        }
    }
}

// ---------------------------------------------------------------------------
// yhat stage 1: partial dot-products of h1 = [y|za|zx] @ [yyw|ayw|xyw].
// grid 104 (2 b x 52 chunks of 32 k), block 128 (one thread per output o).
// Parallelizes the cold-weight fetch across 104 blocks.
// ---------------------------------------------------------------------------
__global__ __launch_bounds__(128) void yhat_partial_kernel(
        const float* __restrict__ y,
        const float* __restrict__ za, const float* __restrict__ zx,
        const float* __restrict__ yyw, const float* __restrict__ ayw,
        const float* __restrict__ xyw,
        float* __restrict__ partial) {
    const int b = blockIdx.x >> 6 ? 1 : 0;         // blockIdx.x / 52
    const int bb = blockIdx.x / 52;
    const int c  = blockIdx.x - bb * 52;
    const int o  = threadIdx.x;
    const int k0 = c * 32;
    float p = 0.f;
    if (k0 < 128) {
#pragma unroll 8
        for (int k = k0; k < k0 + 32; ++k) p += y[bb * YD + k] * yyw[k * YD + o];
    } else if (k0 < 640) {
        const int kk = k0 - 128;
#pragma unroll 8
        for (int k = kk; k < kk + 32; ++k) p += za[bb * 512 + k] * ayw[k * YD + o];
    } else {
        const int kk = k0 - 640;
#pragma unroll 8
        for (int k = kk; k < kk + 32; ++k) p += zx[bb * 1024 + k] * xyw[k * YD + o];
    }
    (void)b;
    partial[(bb * 52 + c) * YD + o] = p;
}

// ---------------------------------------------------------------------------
// yhat stage 2: sum partials + 2-layer MLP. grid 2, block 512 (4-way k-split).
// ---------------------------------------------------------------------------
__global__ __launch_bounds__(512) void yhat_finish_kernel(
        const float* __restrict__ partial,
        const float* __restrict__ yyb, const float* __restrict__ xyb,
        const float* __restrict__ ayb,
        const float* __restrict__ w1, const float* __restrict__ b1,
        const float* __restrict__ w2, const float* __restrict__ b2,
        float* __restrict__ out) {
    const int b = blockIdx.x;
    const int tid = threadIdx.x;
    const int o = tid & 127;
    const int q = tid >> 7;
    __shared__ float red[4][128];
    __shared__ float h1s[128], h2s[128];
    // sum 52 partials, 4-way split (13 each)
    float s = 0.f;
#pragma unroll 13
    for (int c = q * 13; c < q * 13 + 13; ++c)
        s += partial[(b * 52 + c) * YD + o];
    red[q][o] = s;
    __syncthreads();
    if (tid < 128)
        h1s[o] = yyb[o] + xyb[o] + ayb[o] + red[0][o] + red[1][o] + red[2][o] + red[3][o];
    __syncthreads();
    float p2 = 0.f;
#pragma unroll 8
    for (int k = q * 32; k < q * 32 + 32; ++k) p2 += h1s[k] * w1[k * YD + o];
    red[q][o] = p2;
    __syncthreads();
    if (tid < 128) h2s[o] = fmaxf(b1[o] + red[0][o] + red[1][o] + red[2][o] + red[3][o], 0.f);
    __syncthreads();
    float p3 = 0.f;
#pragma unroll 8
    for (int k = q * 32; k < q * 32 + 32; ++k) p3 += h2s[k] * w2[k * YD + o];
    red[q][o] = p3;
    __syncthreads();
    if (tid < 128) out[b * YD + o] = b2[o] + red[0][o] + red[1][o] + red[2][o] + red[3][o];
}

// ---------------------------------------------------------------------------
extern "C" void kernel_launch(void* const* d_in, const int* in_sizes, int n_in,
                              void* d_out, int out_size, void* d_ws, size_t ws_size,
                              hipStream_t stream) {
    const float* x         = (const float*)d_in[0];
    const float* a         = (const float*)d_in[1];
    const float* y         = (const float*)d_in[2];
    const float* qw        = (const float*)d_in[3];  const float* qb        = (const float*)d_in[4];
    const float* kw        = (const float*)d_in[5];  const float* kb        = (const float*)d_in[6];
    const float* vw        = (const float*)d_in[7];  const float* vb        = (const float*)d_in[8];
    const float* a2x_add_w = (const float*)d_in[9];  const float* a2x_add_b = (const float*)d_in[10];
    const float* a2x_mul_w = (const float*)d_in[11]; const float* a2x_mul_b = (const float*)d_in[12];
    const float* y2e_mul_w = (const float*)d_in[13]; const float* y2e_mul_b = (const float*)d_in[14];
    const float* y2e_add_w = (const float*)d_in[15]; const float* y2e_add_b = (const float*)d_in[16];
    const float* y2x_mul_w = (const float*)d_in[17]; const float* y2x_mul_b = (const float*)d_in[18];
    const float* y2x_add_w = (const float*)d_in[19]; const float* y2x_add_b = (const float*)d_in[20];
    const float* y_y_w     = (const float*)d_in[21]; const float* y_y_b     = (const float*)d_in[22];
    const float* x_y_w     = (const float*)d_in[23]; const float* x_y_b     = (const float*)d_in[24];
    const float* a_y_w     = (const float*)d_in[25]; const float* a_y_b     = (const float*)d_in[26];
    const float* x_out_w   = (const float*)d_in[27]; const float* x_out_b   = (const float*)d_in[28];
    const float* a_out_w   = (const float*)d_in[29]; const float* a_out_b   = (const float*)d_in[30];
    const float* y_out1_w  = (const float*)d_in[31]; const float* y_out1_b  = (const float*)d_in[32];
    const float* y_out2_w  = (const float*)d_in[33]; const float* y_out2_b  = (const float*)d_in[34];

    float* ws = (float*)d_ws;
    float* Q      = ws;                                   // 131072
    unsigned short* kvJ = (unsigned short*)(ws + 131072); // 262144 u16 = 131072 f
    float* wV     = ws + 262144;                          // 131072
    float* ye1    = ws + 393216;   // 512
    float* ye2    = ws + 393728;
    float* yx1    = ws + 394240;
    float* yx2    = ws + 394752;
    float* psum   = ws + 395264;   // 65536
    float* psumsq = ws + 460800;
    float* pminb  = ws + 526336;
    float* pmaxb  = ws + 591872;
    float* za     = ws + 657408;   // 1024
    float* zx     = ws + 658432;   // 2048
    unsigned short* WaddT = (unsigned short*)(ws + 660480);  // 32768 u16
    unsigned short* WmulT = (unsigned short*)(ws + 676864);
    unsigned short* W2T   = (unsigned short*)(ws + 693248);
    float* ypart  = ws + 709632;   // 2*52*128 = 13312

    float* xhat = (float*)d_out;
    float* ahat = (float*)d_out + 131072;
    float* yhat = (float*)d_out + 16908288;

    prep_kernel<<<1112, 256, 0, stream>>>(
        x, a, y, qw, qb, kw, kb, vw, vb,
        a2x_add_w, a2x_mul_w, a_out_w,
        y2e_add_w, y2e_add_b, y2e_mul_w, y2e_mul_b,
        y2x_add_w, y2x_add_b, y2x_mul_w, y2x_mul_b,
        Q, kvJ, WaddT, WmulT, W2T,
        ye1, ye2, yx1, yx2,
        psum, psumsq, pminb, pmaxb, zx);
    main_kernel<<<512, 512, 0, stream>>>(a, WaddT, a2x_add_b, WmulT, a2x_mul_b,
                                         W2T, a_out_b, Q, kvJ, ye1, ye2, ahat, wV);
    post_kernel<<<66, 256, 0, stream>>>(wV, yx1, yx2, x_out_w, x_out_b,
                                        psum, psumsq, pminb, pmaxb, xhat, za);
    yhat_partial_kernel<<<104, 128, 0, stream>>>(y, za, zx, y_y_w, a_y_w, x_y_w, ypart);
    yhat_finish_kernel<<<2, 512, 0, stream>>>(ypart, y_y_b, x_y_b, a_y_b,
                                              y_out1_w, y_out1_b, y_out2_w, y_out2_b, yhat);
}